// Round 8
// baseline (151.212 us; speedup 1.0000x reference)
//
#include <hip/hip_runtime.h>

// SpikeEncoder: embedding gather + LayerNorm + LIF scan in FLOAT64
// (harness 'np' reference is f64 — confirmed round 3).
// B=8, S=2048, V=57344, D=1536. Outputs: [spikes (B*S*D), x (B*S*D)] fp32.
//
// Round 8: spikes as u64 bitmasks. The scan kernels write 8B/chunk/chain
// instead of 64 floats (kills the per-step NT store that serialized the
// prefetch pipeline via vmcnt); a separate expand kernel emits the 100 MB
// float tensor at write-roofline. C=32/W=64 unchanged (proven operating pt).

constexpr int Bv = 8, Sv = 2048, Dv = 1536;
constexpr int Cn = 32;              // chunks over S
constexpr int Ln = Sv / Cn;         // 64 steps per chunk (= bits in a u64!)
constexpr int Wn = 64;              // warmup steps (merge horizon — keep!)
constexpr int BD = Bv * Dv;         // 12288 chains
constexpr int TNMAX = Ln + Wn;      // 128 rows max per chunk

// ws layout
constexpr size_t FLAG_OFF  = 0;
constexpr size_t STATS_OFF = 64;                                   // 2*B*S doubles
constexpr size_t SPEC0_OFF = STATS_OFF + (size_t)2 * Bv * Sv * 8;  // start states
constexpr size_t SPEC1_OFF = SPEC0_OFF + (size_t)Cn * BD * 8;      // end states
constexpr size_t BITS_OFF  = SPEC1_OFF + (size_t)Cn * BD * 8;      // spike masks
constexpr size_t WS_NEED   = BITS_OFF + (size_t)Cn * BD * 8;

// ---- shared, bit-exact step functions (identical expression trees) ----
__device__ __forceinline__ double ln_x64(float e, double mu, double rs,
                                         double gd, double bd) {
#pragma clang fp contract(off)
    return (((double)e - mu) * rs) * gd + bd;
}
__device__ __forceinline__ double lif_step(double v, double x, bool& spike) {
#pragma clang fp contract(off)
    double vv = v * 0.95;            // separate mul (np rounding)
    vv = vv + x;                     // separate add
    vv = fmin(fmax(vv, -3.0), 3.0);
    spike = (vv >= 1.0);
    return spike ? 0.0 : vv;
}

// ---------------------------------------------------------------------------
// Kernel 0: detect int64 vs int32 token buffer (tokens < 2^31 => int64 data
// has ALL odd int32 words zero). flag = shift (1 for int64, 0 for int32).
// ---------------------------------------------------------------------------
extern "C" __global__ __launch_bounds__(1024)
void detect_tok64(const int* __restrict__ tok, int* __restrict__ flag)
{
    __shared__ int any_nz;
    if (threadIdx.x == 0) any_nz = 0;
    __syncthreads();
    int nz = 0;
    for (int i = threadIdx.x; i < (Bv * Sv) / 2; i += 1024) nz |= tok[2 * i + 1];
    if (nz) atomicOr(&any_nz, 1);
    __syncthreads();
    if (threadIdx.x == 0) flag[0] = (any_nz == 0) ? 1 : 0;
}

// ---------------------------------------------------------------------------
// Kernel 1: per-row LN stats in f64 (one row per 128-thread block).
// Stores mu,rstd (f64 pair) to stats[], x (f32) to output 1. [unchanged]
// ---------------------------------------------------------------------------
extern "C" __global__ __launch_bounds__(128)
void ln_stats_kernel(const int* __restrict__ tok,
                     const float* __restrict__ emb,
                     const float* __restrict__ gamma,
                     const float* __restrict__ beta,
                     float* __restrict__ x_out,
                     double* __restrict__ stats,
                     const int* __restrict__ tok64_flag)
{
#pragma clang fp contract(off)
    __shared__ double p1[2], p2[2];

    const int row = blockIdx.x;
    const int t   = threadIdx.x;
    const int lane = t & 63, wave = t >> 6;

    const int shift = tok64_flag[0];
    const long long tk = (long long)tok[(size_t)row << shift];
    const float* src = emb + tk * (long long)Dv;

    float4 xv[3];
#pragma unroll
    for (int k = 0; k < 3; ++k) xv[k] = reinterpret_cast<const float4*>(src)[t + 128 * k];

    double s = 0.0;
#pragma unroll
    for (int k = 0; k < 3; ++k) {
        s += (double)xv[k].x; s += (double)xv[k].y;
        s += (double)xv[k].z; s += (double)xv[k].w;
    }
#pragma unroll
    for (int off = 1; off < 64; off <<= 1) s += __shfl_xor(s, off);
    if (lane == 0) p1[wave] = s;
    __syncthreads();
    const double mu = (p1[0] + p1[1]) / 1536.0;

    double q = 0.0;
#pragma unroll
    for (int k = 0; k < 3; ++k) {
        double d0 = (double)xv[k].x - mu; q += d0 * d0;
        double d1 = (double)xv[k].y - mu; q += d1 * d1;
        double d2 = (double)xv[k].z - mu; q += d2 * d2;
        double d3 = (double)xv[k].w - mu; q += d3 * d3;
    }
#pragma unroll
    for (int off = 1; off < 64; off <<= 1) q += __shfl_xor(q, off);
    if (lane == 0) p2[wave] = q;
    __syncthreads();
    const double var  = (p2[0] + p2[1]) / 1536.0;
    const double rstd = 1.0 / sqrt(var + 1e-5);

    if (t == 0) { stats[2 * row] = mu; stats[2 * row + 1] = rstd; }

    float* dst = x_out + (long long)row * Dv;
#pragma unroll
    for (int k = 0; k < 3; ++k) {
        const int f4 = t + 128 * k;
        const float4 g4 = reinterpret_cast<const float4*>(gamma)[f4];
        const float4 b4 = reinterpret_cast<const float4*>(beta)[f4];
        float4 o;
        o.x = (float)((((double)xv[k].x - mu) * rstd) * (double)g4.x + (double)b4.x);
        o.y = (float)((((double)xv[k].y - mu) * rstd) * (double)g4.y + (double)b4.y);
        o.z = (float)((((double)xv[k].z - mu) * rstd) * (double)g4.z + (double)b4.z);
        o.w = (float)((((double)xv[k].w - mu) * rstd) * (double)g4.w + (double)b4.w);
        reinterpret_cast<float4*>(dst)[f4] = o;
    }
}

// ---------------------------------------------------------------------------
// Kernel 2a: speculative LIF chunks -> u64 spike masks (NO float stores in
// the scan loop). Grid = B * Cn * (D/256) = 1536 blocks x 256 threads.
// ---------------------------------------------------------------------------
extern "C" __global__ __launch_bounds__(256)
void lif64_spec(const int* __restrict__ tok,
                const float* __restrict__ emb,
                const float* __restrict__ gamma,
                const float* __restrict__ beta,
                const double* __restrict__ stats,
                double* __restrict__ spec_start,
                double* __restrict__ spec_end,
                unsigned long long* __restrict__ bits,
                const int* __restrict__ tok64_flag)
{
    constexpr int DBLK = Dv / 256;            // 6
    __shared__ int     tokl[TNMAX];
    __shared__ double2 statl[TNMAX];

    const int t    = threadIdx.x;
    const int bid  = blockIdx.x;
    const int dblk = bid % DBLK;
    const int c    = (bid / DBLK) % Cn;
    const int b    = bid / (DBLK * Cn);
    const int d    = dblk * 256 + t;

    const int s0 = c * Ln;
    const int sw = (c == 0) ? 0 : s0 - Wn;
    const int TN = s0 + Ln - sw;              // 64 or 128
    const int warm = s0 - sw;                 // 0 or 64
    const int rowbase = b * Sv;

    // ---- stage row metadata into LDS ----
    if (t < TN) {
        const int row = rowbase + sw + t;
        const int shift = tok64_flag[0];
        tokl[t]  = tok[(size_t)row << shift];                     // token (< 2^31)
        statl[t] = reinterpret_cast<const double2*>(stats)[row];  // {mu, rstd}
    }
    __syncthreads();

    const double gd = (double)gamma[d];
    const double bd = (double)beta[d];

    constexpr int U = 8;
    float ecur[U], enxt[U];
#pragma unroll
    for (int k = 0; k < U; ++k)
        ecur[k] = emb[(long long)tokl[k] * Dv + d];

    double v = 0.0, vstart = 0.0;
    unsigned long long m = 0;
    for (int i = 0; i < TN; i += U) {
        if (i + U < TN) {
#pragma unroll
            for (int k = 0; k < U; ++k)
                enxt[k] = emb[(long long)tokl[i + U + k] * Dv + d];
        }
#pragma unroll
        for (int k = 0; k < U; ++k) {
            const int idx = i + k;
            if (idx == warm) vstart = v;
            const double2 st = statl[idx];
            const double x = ln_x64(ecur[k], st.x, st.y, gd, bd);
            bool spike;
            v = lif_step(v, x, spike);
            if (idx >= warm)
                m |= (unsigned long long)spike << (idx - warm);
        }
#pragma unroll
        for (int k = 0; k < U; ++k) ecur[k] = enxt[k];
    }

    const size_t chain = (size_t)b * Dv + d;
    spec_start[(size_t)c * BD + chain] = vstart;
    spec_end[(size_t)c * BD + chain]   = v;
    bits[(size_t)c * BD + chain]       = m;
}

// ---------------------------------------------------------------------------
// Kernel 2b: exact fixup on masks. One thread per chain. Bitwise-equal entry
// state => chunk provably exact; else recompute the chunk's mask (8-deep
// prefetch) and overwrite bits. Cascades handled naturally.
// ---------------------------------------------------------------------------
extern "C" __global__ __launch_bounds__(64)
void lif64_fixup(const int* __restrict__ tok,
                 const float* __restrict__ emb,
                 const float* __restrict__ gamma,
                 const float* __restrict__ beta,
                 const double* __restrict__ stats,
                 const double* __restrict__ spec_start,
                 const double* __restrict__ spec_end,
                 unsigned long long* __restrict__ bits,
                 const int* __restrict__ tok64_flag)
{
    const int gid = blockIdx.x * 64 + threadIdx.x;   // chain id
    const int b = gid / Dv;
    const int d = gid - b * Dv;
    const int shift = tok64_flag[0];
    const double gd = (double)gamma[d];
    const double bd = (double)beta[d];
    const int rowbase = b * Sv;

    double v = 0.0;
    for (int c = 0; c < Cn; ++c) {
        const double vs = spec_start[(size_t)c * BD + gid];
        const double ve = spec_end[(size_t)c * BD + gid];
        if (v == vs) { v = ve; continue; }
        // recompute chunk c (rare): 8-deep prefetched, mask only
        constexpr int U = 8;
        const int s0 = c * Ln;
        float  ecur[U], enxt[U];
        double mcur[U], mnxt[U], rcur[U], rnxt[U];
#pragma unroll
        for (int k = 0; k < U; ++k) {
            const int row = rowbase + s0 + k;
            const long long tk = (long long)tok[(size_t)row << shift];
            ecur[k] = emb[tk * (long long)Dv + d];
            mcur[k] = stats[2 * row];
            rcur[k] = stats[2 * row + 1];
        }
        unsigned long long m = 0;
        for (int i = 0; i < Ln; i += U) {
            if (i + U < Ln) {
#pragma unroll
                for (int k = 0; k < U; ++k) {
                    const int row = rowbase + s0 + i + U + k;
                    const long long tk = (long long)tok[(size_t)row << shift];
                    enxt[k] = emb[tk * (long long)Dv + d];
                    mnxt[k] = stats[2 * row];
                    rnxt[k] = stats[2 * row + 1];
                }
            }
#pragma unroll
            for (int k = 0; k < U; ++k) {
                const double x = ln_x64(ecur[k], mcur[k], rcur[k], gd, bd);
                bool spike;
                v = lif_step(v, x, spike);
                m |= (unsigned long long)spike << (i + k);
            }
#pragma unroll
            for (int k = 0; k < U; ++k) {
                ecur[k] = enxt[k]; mcur[k] = mnxt[k]; rcur[k] = rnxt[k];
            }
        }
        bits[(size_t)c * BD + gid] = m;
    }
}

// ---------------------------------------------------------------------------
// Kernel 3: expand bitmasks -> float spike tensor. Pure streaming writes.
// Grid = B * Cn * (D/256) blocks x 256; each thread owns one (b,c,d) mask.
// ---------------------------------------------------------------------------
extern "C" __global__ __launch_bounds__(256)
void spike_expand(const unsigned long long* __restrict__ bits,
                  float* __restrict__ spk)
{
    constexpr int DBLK = Dv / 256;            // 6
    const int t    = threadIdx.x;
    const int bid  = blockIdx.x;
    const int dblk = bid % DBLK;
    const int c    = (bid / DBLK) % Cn;
    const int b    = bid / (DBLK * Cn);
    const int d    = dblk * 256 + t;

    const unsigned long long m = bits[(size_t)c * BD + (size_t)b * Dv + d];
    float* sp = spk + ((size_t)b * Sv + (size_t)c * Ln) * Dv + d;
#pragma unroll
    for (int s = 0; s < Ln; ++s)
        __builtin_nontemporal_store(((m >> s) & 1ull) ? 1.0f : 0.0f,
                                    &sp[(size_t)s * Dv]);
}

// ---------------------------------------------------------------------------
// Fallback: sequential LIF (round-3 version, bit-identical step math).
// Used only if ws is too small for the speculative state arrays.
// ---------------------------------------------------------------------------
extern "C" __global__ __launch_bounds__(64)
void lif64_seq(const int* __restrict__ tok,
               const float* __restrict__ emb,
               const float* __restrict__ gamma,
               const float* __restrict__ beta,
               const double* __restrict__ stats,
               float* __restrict__ spk,
               const int* __restrict__ tok64_flag)
{
    const int gid = blockIdx.x * 64 + threadIdx.x;
    const int b = gid / Dv;
    const int d = gid - b * Dv;
    const int shift = tok64_flag[0];
    const int rowbase = b * Sv;
    const double gd = (double)gamma[d];
    const double bd = (double)beta[d];
    float* sp = spk + (size_t)b * Sv * Dv + d;

    constexpr int U = 8;
    float  ecur[U], enxt[U];
    double mcur[U], mnxt[U], rcur[U], rnxt[U];
#pragma unroll
    for (int k = 0; k < U; ++k) {
        const int row = rowbase + k;
        const long long tk = (long long)tok[(size_t)row << shift];
        ecur[k] = emb[tk * (long long)Dv + d];
        mcur[k] = stats[2 * row];
        rcur[k] = stats[2 * row + 1];
    }
    double v = 0.0;
    for (int s = 0; s < Sv; s += U) {
        if (s + U < Sv) {
#pragma unroll
            for (int k = 0; k < U; ++k) {
                const int row = rowbase + s + U + k;
                const long long tk = (long long)tok[(size_t)row << shift];
                enxt[k] = emb[tk * (long long)Dv + d];
                mnxt[k] = stats[2 * row];
                rnxt[k] = stats[2 * row + 1];
            }
        }
#pragma unroll
        for (int k = 0; k < U; ++k) {
            const double x = ln_x64(ecur[k], mcur[k], rcur[k], gd, bd);
            bool spike;
            v = lif_step(v, x, spike);
            __builtin_nontemporal_store(spike ? 1.0f : 0.0f, &sp[(size_t)(s + k) * Dv]);
        }
#pragma unroll
        for (int k = 0; k < U; ++k) { ecur[k] = enxt[k]; mcur[k] = mnxt[k]; rcur[k] = rnxt[k]; }
    }
}

extern "C" void kernel_launch(void* const* d_in, const int* in_sizes, int n_in,
                              void* d_out, int out_size, void* d_ws, size_t ws_size,
                              hipStream_t stream)
{
    const int*   tok   = (const int*)  d_in[0];
    const float* emb   = (const float*)d_in[1];
    const float* gamma = (const float*)d_in[2];
    const float* beta  = (const float*)d_in[3];

    float* out = (float*)d_out;
    float* spk = out;                               // output 0: spikes
    float* x   = out + (size_t)Bv * Sv * Dv;        // output 1: x (LN result)

    int*    flg   = (int*)((char*)d_ws + FLAG_OFF);
    double* stats = (double*)((char*)d_ws + STATS_OFF);

    detect_tok64<<<1, 1024, 0, stream>>>(tok, flg);
    ln_stats_kernel<<<Bv * Sv, 128, 0, stream>>>(tok, emb, gamma, beta, x, stats, flg);

    if (ws_size >= WS_NEED) {
        double* spec0 = (double*)((char*)d_ws + SPEC0_OFF);
        double* spec1 = (double*)((char*)d_ws + SPEC1_OFF);
        unsigned long long* bits = (unsigned long long*)((char*)d_ws + BITS_OFF);
        lif64_spec<<<Bv * Cn * (Dv / 256), 256, 0, stream>>>(
            tok, emb, gamma, beta, stats, spec0, spec1, bits, flg);
        lif64_fixup<<<BD / 64, 64, 0, stream>>>(
            tok, emb, gamma, beta, stats, spec0, spec1, bits, flg);
        spike_expand<<<Bv * Cn * (Dv / 256), 256, 0, stream>>>(bits, spk);
    } else {
        lif64_seq<<<BD / 64, 64, 0, stream>>>(tok, emb, gamma, beta, stats, spk, flg);
    }
}

// Round 9
// 117.428 us; speedup vs baseline: 1.2877x; 1.2877x over previous
//
#include <hip/hip_runtime.h>

// SpikeEncoder: embedding gather + LayerNorm + LIF scan in FLOAT64
// (harness 'np' reference is f64 — confirmed round 3).
// B=8, S=2048, V=57344, D=1536. Outputs: [spikes (B*S*D), x (B*S*D)] fp32.
//
// Round 9: revert round-8's bitmask/expand (+32 µs regression — stores were
// not the bottleneck). Round-7 structure (C=32/W=64, direct float stores,
// LDS row metadata) + deeper prefetch U=16 in spec: per 8-step batch the
// ~900-cyc gather latency exceeded ~350 cyc of per-wave work; 16 outstanding
// loads give two compute batches per latency window. launch_bounds(256,6)
// pins >=6 waves/SIMD so the larger buffers can't drop residency.

constexpr int Bv = 8, Sv = 2048, Dv = 1536;
constexpr int Cn = 32;              // chunks over S (1536 blocks = resident capacity)
constexpr int Ln = Sv / Cn;         // 64 steps per chunk
constexpr int Wn = 64;              // warmup steps (merge horizon — keep!)
constexpr int BD = Bv * Dv;         // 12288 chains
constexpr int TNMAX = Ln + Wn;      // 128 rows max per chunk

// ws layout
constexpr size_t FLAG_OFF  = 0;
constexpr size_t STATS_OFF = 64;                                   // 2*B*S doubles
constexpr size_t SPEC0_OFF = STATS_OFF + (size_t)2 * Bv * Sv * 8;  // start states
constexpr size_t SPEC1_OFF = SPEC0_OFF + (size_t)Cn * BD * 8;      // end states
constexpr size_t WS_NEED   = SPEC1_OFF + (size_t)Cn * BD * 8;

// ---- shared, bit-exact step functions (identical expression trees) ----
__device__ __forceinline__ double ln_x64(float e, double mu, double rs,
                                         double gd, double bd) {
#pragma clang fp contract(off)
    return (((double)e - mu) * rs) * gd + bd;
}
__device__ __forceinline__ double lif_step(double v, double x, bool& spike) {
#pragma clang fp contract(off)
    double vv = v * 0.95;            // separate mul (np rounding)
    vv = vv + x;                     // separate add
    vv = fmin(fmax(vv, -3.0), 3.0);
    spike = (vv >= 1.0);
    return spike ? 0.0 : vv;
}

// ---------------------------------------------------------------------------
// Kernel 0: detect int64 vs int32 token buffer (tokens < 2^31 => int64 data
// has ALL odd int32 words zero). flag = shift (1 for int64, 0 for int32).
// ---------------------------------------------------------------------------
extern "C" __global__ __launch_bounds__(1024)
void detect_tok64(const int* __restrict__ tok, int* __restrict__ flag)
{
    __shared__ int any_nz;
    if (threadIdx.x == 0) any_nz = 0;
    __syncthreads();
    int nz = 0;
    for (int i = threadIdx.x; i < (Bv * Sv) / 2; i += 1024) nz |= tok[2 * i + 1];
    if (nz) atomicOr(&any_nz, 1);
    __syncthreads();
    if (threadIdx.x == 0) flag[0] = (any_nz == 0) ? 1 : 0;
}

// ---------------------------------------------------------------------------
// Kernel 1: per-row LN stats in f64 (one row per 128-thread block).
// Stores mu,rstd (f64 pair) to stats[], x (f32) to output 1. [unchanged]
// ---------------------------------------------------------------------------
extern "C" __global__ __launch_bounds__(128)
void ln_stats_kernel(const int* __restrict__ tok,
                     const float* __restrict__ emb,
                     const float* __restrict__ gamma,
                     const float* __restrict__ beta,
                     float* __restrict__ x_out,
                     double* __restrict__ stats,
                     const int* __restrict__ tok64_flag)
{
#pragma clang fp contract(off)
    __shared__ double p1[2], p2[2];

    const int row = blockIdx.x;
    const int t   = threadIdx.x;
    const int lane = t & 63, wave = t >> 6;

    const int shift = tok64_flag[0];
    const long long tk = (long long)tok[(size_t)row << shift];
    const float* src = emb + tk * (long long)Dv;

    float4 xv[3];
#pragma unroll
    for (int k = 0; k < 3; ++k) xv[k] = reinterpret_cast<const float4*>(src)[t + 128 * k];

    double s = 0.0;
#pragma unroll
    for (int k = 0; k < 3; ++k) {
        s += (double)xv[k].x; s += (double)xv[k].y;
        s += (double)xv[k].z; s += (double)xv[k].w;
    }
#pragma unroll
    for (int off = 1; off < 64; off <<= 1) s += __shfl_xor(s, off);
    if (lane == 0) p1[wave] = s;
    __syncthreads();
    const double mu = (p1[0] + p1[1]) / 1536.0;

    double q = 0.0;
#pragma unroll
    for (int k = 0; k < 3; ++k) {
        double d0 = (double)xv[k].x - mu; q += d0 * d0;
        double d1 = (double)xv[k].y - mu; q += d1 * d1;
        double d2 = (double)xv[k].z - mu; q += d2 * d2;
        double d3 = (double)xv[k].w - mu; q += d3 * d3;
    }
#pragma unroll
    for (int off = 1; off < 64; off <<= 1) q += __shfl_xor(q, off);
    if (lane == 0) p2[wave] = q;
    __syncthreads();
    const double var  = (p2[0] + p2[1]) / 1536.0;
    const double rstd = 1.0 / sqrt(var + 1e-5);

    if (t == 0) { stats[2 * row] = mu; stats[2 * row + 1] = rstd; }

    float* dst = x_out + (long long)row * Dv;
#pragma unroll
    for (int k = 0; k < 3; ++k) {
        const int f4 = t + 128 * k;
        const float4 g4 = reinterpret_cast<const float4*>(gamma)[f4];
        const float4 b4 = reinterpret_cast<const float4*>(beta)[f4];
        float4 o;
        o.x = (float)((((double)xv[k].x - mu) * rstd) * (double)g4.x + (double)b4.x);
        o.y = (float)((((double)xv[k].y - mu) * rstd) * (double)g4.y + (double)b4.y);
        o.z = (float)((((double)xv[k].z - mu) * rstd) * (double)g4.z + (double)b4.z);
        o.w = (float)((((double)xv[k].w - mu) * rstd) * (double)g4.w + (double)b4.w);
        reinterpret_cast<float4*>(dst)[f4] = o;
    }
}

// ---------------------------------------------------------------------------
// Kernel 2a: speculative LIF chunks. Grid = B * Cn * (D/256) = 1536 blocks
// x 256 (= resident capacity at 6 waves/SIMD). LDS-staged row metadata;
// U=16-deep prefetched emb gathers; direct NT float spike stores.
// ---------------------------------------------------------------------------
extern "C" __global__ __launch_bounds__(256, 6)
void lif64_spec(const int* __restrict__ tok,
                const float* __restrict__ emb,
                const float* __restrict__ gamma,
                const float* __restrict__ beta,
                const double* __restrict__ stats,
                float* __restrict__ spk,
                double* __restrict__ spec_start,
                double* __restrict__ spec_end,
                const int* __restrict__ tok64_flag)
{
    constexpr int DBLK = Dv / 256;            // 6
    __shared__ int     tokl[TNMAX];
    __shared__ double2 statl[TNMAX];

    const int t    = threadIdx.x;
    const int bid  = blockIdx.x;
    const int dblk = bid % DBLK;
    const int c    = (bid / DBLK) % Cn;
    const int b    = bid / (DBLK * Cn);
    const int d    = dblk * 256 + t;

    const int s0 = c * Ln;
    const int sw = (c == 0) ? 0 : s0 - Wn;
    const int TN = s0 + Ln - sw;              // 64 or 128
    const int warm = s0 - sw;                 // 0 or 64
    const int rowbase = b * Sv;

    // ---- stage row metadata into LDS ----
    if (t < TN) {
        const int row = rowbase + sw + t;
        const int shift = tok64_flag[0];
        tokl[t]  = tok[(size_t)row << shift];                     // token (< 2^31)
        statl[t] = reinterpret_cast<const double2*>(stats)[row];  // {mu, rstd}
    }
    __syncthreads();

    const double gd = (double)gamma[d];
    const double bd = (double)beta[d];
    float* sp = spk + (size_t)b * Sv * Dv + d;

    constexpr int U = 16;
    float ecur[U], enxt[U];
#pragma unroll
    for (int k = 0; k < U; ++k)
        ecur[k] = emb[(long long)tokl[k] * Dv + d];

    double v = 0.0, vstart = 0.0;
    for (int i = 0; i < TN; i += U) {
        if (i + U < TN) {
#pragma unroll
            for (int k = 0; k < U; ++k)
                enxt[k] = emb[(long long)tokl[i + U + k] * Dv + d];
        }
#pragma unroll
        for (int k = 0; k < U; ++k) {
            const int idx = i + k;
            if (idx == warm) vstart = v;
            const double2 st = statl[idx];
            const double x = ln_x64(ecur[k], st.x, st.y, gd, bd);
            bool spike;
            const double vn = lif_step(v, x, spike);
            if (idx >= warm)
                __builtin_nontemporal_store(spike ? 1.0f : 0.0f,
                                            &sp[(size_t)(sw + idx) * Dv]);
            v = vn;
        }
#pragma unroll
        for (int k = 0; k < U; ++k) ecur[k] = enxt[k];
    }

    const size_t chain = (size_t)b * Dv + d;
    spec_start[(size_t)c * BD + chain] = vstart;
    spec_end[(size_t)c * BD + chain]   = v;
}

// ---------------------------------------------------------------------------
// Kernel 2b: exact fixup. One thread per chain. Walk chunks; bitwise-equal
// entry state => chunk's spikes provably exact, jump via exit state; else
// recompute the chunk with 8-deep prefetch (rare).
// ---------------------------------------------------------------------------
extern "C" __global__ __launch_bounds__(64)
void lif64_fixup(const int* __restrict__ tok,
                 const float* __restrict__ emb,
                 const float* __restrict__ gamma,
                 const float* __restrict__ beta,
                 const double* __restrict__ stats,
                 const double* __restrict__ spec_start,
                 const double* __restrict__ spec_end,
                 float* __restrict__ spk,
                 const int* __restrict__ tok64_flag)
{
    const int gid = blockIdx.x * 64 + threadIdx.x;   // chain id
    const int b = gid / Dv;
    const int d = gid - b * Dv;
    const int shift = tok64_flag[0];
    const double gd = (double)gamma[d];
    const double bd = (double)beta[d];
    const int rowbase = b * Sv;
    float* sp = spk + (size_t)b * Sv * Dv + d;

    double v = 0.0;
    for (int c = 0; c < Cn; ++c) {
        const double vs = spec_start[(size_t)c * BD + gid];
        const double ve = spec_end[(size_t)c * BD + gid];
        if (v == vs) { v = ve; continue; }
        // recompute chunk c (rare): 8-deep prefetched
        constexpr int U = 8;
        const int s0 = c * Ln;
        float  ecur[U], enxt[U];
        double mcur[U], mnxt[U], rcur[U], rnxt[U];
#pragma unroll
        for (int k = 0; k < U; ++k) {
            const int row = rowbase + s0 + k;
            const long long tk = (long long)tok[(size_t)row << shift];
            ecur[k] = emb[tk * (long long)Dv + d];
            mcur[k] = stats[2 * row];
            rcur[k] = stats[2 * row + 1];
        }
        for (int i = 0; i < Ln; i += U) {
            if (i + U < Ln) {
#pragma unroll
                for (int k = 0; k < U; ++k) {
                    const int row = rowbase + s0 + i + U + k;
                    const long long tk = (long long)tok[(size_t)row << shift];
                    enxt[k] = emb[tk * (long long)Dv + d];
                    mnxt[k] = stats[2 * row];
                    rnxt[k] = stats[2 * row + 1];
                }
            }
#pragma unroll
            for (int k = 0; k < U; ++k) {
                const double x = ln_x64(ecur[k], mcur[k], rcur[k], gd, bd);
                bool spike;
                v = lif_step(v, x, spike);
                sp[(size_t)(s0 + i + k) * Dv] = spike ? 1.0f : 0.0f;
            }
#pragma unroll
            for (int k = 0; k < U; ++k) {
                ecur[k] = enxt[k]; mcur[k] = mnxt[k]; rcur[k] = rnxt[k];
            }
        }
    }
}

// ---------------------------------------------------------------------------
// Fallback: sequential LIF (round-3 version, bit-identical step math).
// Used only if ws is too small for the speculative state arrays.
// ---------------------------------------------------------------------------
extern "C" __global__ __launch_bounds__(64)
void lif64_seq(const int* __restrict__ tok,
               const float* __restrict__ emb,
               const float* __restrict__ gamma,
               const float* __restrict__ beta,
               const double* __restrict__ stats,
               float* __restrict__ spk,
               const int* __restrict__ tok64_flag)
{
    const int gid = blockIdx.x * 64 + threadIdx.x;
    const int b = gid / Dv;
    const int d = gid - b * Dv;
    const int shift = tok64_flag[0];
    const int rowbase = b * Sv;
    const double gd = (double)gamma[d];
    const double bd = (double)beta[d];
    float* sp = spk + (size_t)b * Sv * Dv + d;

    constexpr int U = 8;
    float  ecur[U], enxt[U];
    double mcur[U], mnxt[U], rcur[U], rnxt[U];
#pragma unroll
    for (int k = 0; k < U; ++k) {
        const int row = rowbase + k;
        const long long tk = (long long)tok[(size_t)row << shift];
        ecur[k] = emb[tk * (long long)Dv + d];
        mcur[k] = stats[2 * row];
        rcur[k] = stats[2 * row + 1];
    }
    double v = 0.0;
    for (int s = 0; s < Sv; s += U) {
        if (s + U < Sv) {
#pragma unroll
            for (int k = 0; k < U; ++k) {
                const int row = rowbase + s + U + k;
                const long long tk = (long long)tok[(size_t)row << shift];
                enxt[k] = emb[tk * (long long)Dv + d];
                mnxt[k] = stats[2 * row];
                rnxt[k] = stats[2 * row + 1];
            }
        }
#pragma unroll
        for (int k = 0; k < U; ++k) {
            const double x = ln_x64(ecur[k], mcur[k], rcur[k], gd, bd);
            bool spike;
            v = lif_step(v, x, spike);
            __builtin_nontemporal_store(spike ? 1.0f : 0.0f, &sp[(size_t)(s + k) * Dv]);
        }
#pragma unroll
        for (int k = 0; k < U; ++k) { ecur[k] = enxt[k]; mcur[k] = mnxt[k]; rcur[k] = rnxt[k]; }
    }
}

extern "C" void kernel_launch(void* const* d_in, const int* in_sizes, int n_in,
                              void* d_out, int out_size, void* d_ws, size_t ws_size,
                              hipStream_t stream)
{
    const int*   tok   = (const int*)  d_in[0];
    const float* emb   = (const float*)d_in[1];
    const float* gamma = (const float*)d_in[2];
    const float* beta  = (const float*)d_in[3];

    float* out = (float*)d_out;
    float* spk = out;                               // output 0: spikes
    float* x   = out + (size_t)Bv * Sv * Dv;        // output 1: x (LN result)

    int*    flg   = (int*)((char*)d_ws + FLAG_OFF);
    double* stats = (double*)((char*)d_ws + STATS_OFF);

    detect_tok64<<<1, 1024, 0, stream>>>(tok, flg);
    ln_stats_kernel<<<Bv * Sv, 128, 0, stream>>>(tok, emb, gamma, beta, x, stats, flg);

    if (ws_size >= WS_NEED) {
        double* spec0 = (double*)((char*)d_ws + SPEC0_OFF);
        double* spec1 = (double*)((char*)d_ws + SPEC1_OFF);
        lif64_spec<<<Bv * Cn * (Dv / 256), 256, 0, stream>>>(
            tok, emb, gamma, beta, stats, spk, spec0, spec1, flg);
        lif64_fixup<<<BD / 64, 64, 0, stream>>>(
            tok, emb, gamma, beta, stats, spec0, spec1, spk, flg);
    } else {
        lif64_seq<<<BD / 64, 64, 0, stream>>>(tok, emb, gamma, beta, stats, spk, flg);
    }
}